// Round 7
// baseline (16942.084 us; speedup 1.0000x reference)
//
#include <hip/hip_runtime.h>
#include <hip/hip_bf16.h>

// Problem constants
#define B_    512
#define HIST_ 8
#define PRED_ 24
#define CITY_ 184
#define FEAT_ 13
#define HID_  32
#define BC_   (B_*CITY_)   // 94208 = 1472 blocks * 4 waves * 16 seqs
#define FLAG_OFF 7168

// ws (float) layout (written by prep_all):
//   [0..4095]      Wh2[row*32+k] : W_hh + a0 (x) W_out   (all t; h=0 at t=0)
//   [4096..6143]   Wf [row*16+f] : W_x[:,1:14], cols 13..15 zeroed
//   [6144..6271]   bg2[row]      : b_g + a0*b_out
//   [6272..6399]   a0 [row]      : W_x[:,0]
//   [6400..6527]   bg0[row]      : b_g (unused by main, kept for layout)
//   [6528..6559]   wout[k]
//   [6560]         bout
//   [7168]         dtype flag: 0.0f = bf16 inputs, 1.0f = fp32 inputs

typedef float v4 __attribute__((ext_vector_type(4)));

__device__ __forceinline__ float rcp_(float x) { return __builtin_amdgcn_rcpf(x); }
__device__ __forceinline__ float sigf(float x) { return rcp_(1.0f + __expf(-x)); }
__device__ __forceinline__ float tanhf_(float x) {
    float e = __expf(2.0f * x);
    return 1.0f - 2.0f * rcp_(e + 1.0f);   // saturates correctly
}

template<bool F32>
__device__ __forceinline__ float ldin(const void* p, long i) {
    if constexpr (F32) return ((const float*)p)[i];
    else               return __bfloat162float(((const __hip_bfloat16*)p)[i]);
}
template<bool F32>
__device__ __forceinline__ void stout(void* p, long i, float v) {
    if constexpr (F32) ((float*)p)[i] = v;
    else               ((__hip_bfloat16*)p)[i] = __float2bfloat16(v);
}

// ---- weight folding (validated R2-R6) ----
template<bool F32>
__device__ __forceinline__ void prep_body(
    const void* __restrict__ W_in,  const void* __restrict__ b_in,
    const void* __restrict__ W_out, const void* __restrict__ b_out,
    const void* __restrict__ W_ih,  const void* __restrict__ W_hh,
    const void* __restrict__ b_ih,  const void* __restrict__ b_hh,
    float* __restrict__ ws, int j)
{
    float wx[14];
    #pragma unroll
    for (int c = 0; c < 14; ++c) wx[c] = 0.0f;
    float bg = ldin<F32>(b_ih, j) + ldin<F32>(b_hh, j);
    #pragma unroll
    for (int m = 0; m < 32; ++m) {
        float wihm = ldin<F32>(W_ih, j*32 + m);
        #pragma unroll
        for (int c = 0; c < 14; ++c) wx[c] = fmaf(wihm, ldin<F32>(W_in, m*14 + c), wx[c]);
        bg = fmaf(wihm, ldin<F32>(b_in, m), bg);
    }
    float a0 = wx[0];
    #pragma unroll
    for (int k = 0; k < 32; ++k)
        ws[j*32 + k] = ldin<F32>(W_hh, j*32 + k) + a0 * ldin<F32>(W_out, k);
    #pragma unroll
    for (int f = 0; f < 13; ++f) ws[4096 + j*16 + f] = wx[1 + f];
    #pragma unroll
    for (int f = 13; f < 16; ++f) ws[4096 + j*16 + f] = 0.0f;  // pad MUST be 0
    float bo = ldin<F32>(b_out, 0);
    ws[6144 + j] = bg + a0 * bo;
    ws[6272 + j] = a0;
    ws[6400 + j] = bg;
    if (j < 32) ws[6528 + j] = ldin<F32>(W_out, j);
    if (j == 0) ws[6560] = bo;
}

// Single dispatch: dtype detect (validated R2-R6) + fold.
__global__ void prep_all(const unsigned short* __restrict__ feat_raw,
                         const void* __restrict__ W_in,  const void* __restrict__ b_in,
                         const void* __restrict__ W_out, const void* __restrict__ b_out,
                         const void* __restrict__ W_ih,  const void* __restrict__ W_hh,
                         const void* __restrict__ b_ih,  const void* __restrict__ b_hh,
                         float* __restrict__ ws)
{
    __shared__ int cnt;
    const int tid = threadIdx.x;     // 128 threads
    if (tid == 0) cnt = 0;
    __syncthreads();
    int insane = 0;
    for (int i = tid; i < 4096; i += 128) {
        float v = __uint_as_float(((unsigned int)feat_raw[i]) << 16);
        if (!(fabsf(v) < 1e8f)) insane++;   // catches NaN too
    }
    if (insane) atomicAdd(&cnt, insane);
    __syncthreads();
    const bool f32 = (cnt > 8);
    if (tid == 0) ws[FLAG_OFF] = f32 ? 1.0f : 0.0f;
    if (f32) prep_body<true >(W_in,b_in,W_out,b_out,W_ih,W_hh,b_ih,b_hh,ws,tid);
    else     prep_body<false>(W_in,b_in,W_out,b_out,W_ih,W_hh,b_ih,b_hh,ws,tid);
}

// Sequence-parallel LSTM: 4 lanes per sequence, lane owns 8 units (all 4
// gate rows). Weights STREAMED from L1 (addresses depend only on lane&3 ->
// 4 distinct cache lines per load instr). State in registers; no LDS.
template<bool F32>
__device__ __forceinline__ void lstm_body(
    const void* __restrict__ pm25, const void* __restrict__ feat,
    const float* __restrict__ ws, void* __restrict__ out,
    const int lane, const int wseq)
{
    const int q    = lane & 3;          // unit block: units q*8 .. q*8+7
    const int sl   = lane >> 2;         // seq slot 0..15
    const int seq  = wseq + sl;
    const int b    = seq / CITY_;
    const int city = seq - b*CITY_;

    const float bo = ws[6560];
    float wo8[8];                        // wout for own units
    #pragma unroll
    for (int i = 0; i < 8; ++i) wo8[i] = ws[6528 + q*8 + i];

    const float x0 = ldin<F32>(pm25, (long)(b*HIST_ + (HIST_-1))*CITY_ + city);
    const float xb = x0 - bo;            // t=0 fold: bg0 + a0*x0 == bg2 + a0*(x0-bo)

    long fbase = ((long)(b*(HIST_+PRED_) + HIST_)*CITY_ + city)*FEAT_;
    const long obase = (long)b*(PRED_*CITY_) + city;

    float h[32], c[8];
    #pragma unroll
    for (int k = 0; k < 32; ++k) h[k] = 0.0f;
    #pragma unroll
    for (int i = 0; i < 8; ++i) c[i] = 0.0f;

    #pragma unroll 1
    for (int t = 0; t < PRED_; ++t) {
        float f[16];                     // padded to 16; pad cols of Wf are 0
        #pragma unroll
        for (int i = 0; i < FEAT_; ++i) f[i] = ldin<F32>(feat, fbase + i);
        f[13] = 0.0f; f[14] = 0.0f; f[15] = 0.0f;
        fbase += CITY_*FEAT_;

        const float xsel = (t == 0) ? xb : 0.0f;

        float hn[8];
        #pragma unroll
        for (int j = 0; j < 8; ++j) {
            const int U = q*8 + j;
            float acc[4];
            #pragma unroll
            for (int g = 0; g < 4; ++g) {
                const int row = U + 32*g;
                float a = fmaf(ws[6272 + row], xsel, ws[6144 + row]);
                const v4* wr = (const v4*)(ws + row*32);       // 8 x float4
                #pragma unroll
                for (int kq = 0; kq < 8; ++kq) {
                    const v4 w = wr[kq];
                    a = fmaf(w.x, h[kq*4+0], a);
                    a = fmaf(w.y, h[kq*4+1], a);
                    a = fmaf(w.z, h[kq*4+2], a);
                    a = fmaf(w.w, h[kq*4+3], a);
                }
                const v4* wf = (const v4*)(ws + 4096 + row*16); // 4 x float4
                #pragma unroll
                for (int kq = 0; kq < 4; ++kq) {
                    const v4 w = wf[kq];
                    a = fmaf(w.x, f[kq*4+0], a);
                    a = fmaf(w.y, f[kq*4+1], a);
                    a = fmaf(w.z, f[kq*4+2], a);
                    a = fmaf(w.w, f[kq*4+3], a);
                }
                acc[g] = a;
            }
            const float I = sigf(acc[0]);
            const float F = sigf(acc[1]);
            const float G = tanhf_(acc[2]);
            const float O = sigf(acc[3]);
            const float cc = fmaf(F, c[j], I*G);   // c=0 at t=0 -> F-term dies
            c[j] = cc;
            hn[j] = O * tanhf_(cc);
        }

        // h exchange within the 4-lane group: h[m*8+i] = lane(base+m).hn[i]
        const int lb = lane & ~3;
        #pragma unroll
        for (int m = 0; m < 4; ++m) {
            #pragma unroll
            for (int i = 0; i < 8; ++i)
                h[m*8 + i] = __shfl(hn[i], lb + m);
        }

        // y_t = wout . h_{t+1} + bout : partial dot + 2-level reduce
        float y = 0.0f;
        #pragma unroll
        for (int i = 0; i < 8; ++i) y = fmaf(wo8[i], hn[i], y);
        y += __shfl_xor(y, 1);
        y += __shfl_xor(y, 2);
        if (q == 0) stout<F32>(out, obase + (long)t*CITY_, y + bo);
    }
}

__global__ __launch_bounds__(256)
void lstm_main(const void* __restrict__ pm25, const void* __restrict__ feat,
               const float* __restrict__ ws, void* __restrict__ out)
{
    const int lane = threadIdx.x & 63;
    const int wave = threadIdx.x >> 6;
    const int wseq = (blockIdx.x * 4 + wave) * 16;
    const bool f32 = (ws[FLAG_OFF] != 0.0f);
    if (f32) lstm_body<true >(pm25, feat, ws, out, lane, wseq);
    else     lstm_body<false>(pm25, feat, ws, out, lane, wseq);
}

extern "C" void kernel_launch(void* const* d_in, const int* in_sizes, int n_in,
                              void* d_out, int out_size, void* d_ws, size_t ws_size,
                              hipStream_t stream) {
    const void* pm25  = d_in[0];
    const void* feat  = d_in[1];
    float* ws = (float*)d_ws;

    prep_all<<<dim3(1), dim3(128), 0, stream>>>(
        (const unsigned short*)feat,
        d_in[2], d_in[3], d_in[4], d_in[5], d_in[6], d_in[7], d_in[8], d_in[9],
        ws);

    lstm_main<<<dim3(BC_/64), dim3(256), 0, stream>>>(pm25, feat, ws, d_out);
}